// Round 1
// baseline (1467.781 us; speedup 1.0000x reference)
//
#include <hip/hip_runtime.h>

#define F_IN 2
#define H 16
#define C 10
#define G_GRAPHS 1024

// ---- degree: deg[dst] += 1 per edge ----
__global__ void k_deg(const int* __restrict__ dst, int* __restrict__ deg, int E) {
    int e = blockIdx.x * blockDim.x + threadIdx.x;
    if (e < E) atomicAdd(&deg[dst[e]], 1);
}

// ---- dis[n] = rsqrt(deg[n] + 1)  (self-loop included) ----
__global__ void k_dis(const int* __restrict__ deg, float* __restrict__ dis, int n) {
    int i = blockIdx.x * blockDim.x + threadIdx.x;
    if (i < n) dis[i] = rsqrtf((float)(deg[i] + 1));
}

// ---- layer-1 linear: hs[n][j] = (x[n][0]*W1[0][j] + x[n][1]*W1[1][j]) * dis[n] ----
__global__ void k_lin1(const float* __restrict__ x, const float* __restrict__ W1,
                       const float* __restrict__ dis, float* __restrict__ hs, int n) {
    int i = blockIdx.x * blockDim.x + threadIdx.x;
    if (i >= n * H) return;
    int node = i >> 4, j = i & 15;
    float v = x[node * 2 + 0] * W1[j] + x[node * 2 + 1] * W1[H + j];
    hs[i] = v * dis[node];
}

// ---- edge scatter: t[dst][j] += hs[src][j]; 16 consecutive threads per edge ----
__global__ void k_scatter(const int* __restrict__ src, const int* __restrict__ dst,
                          const float* __restrict__ hs, float* __restrict__ t,
                          long total) {
    long i = (long)blockIdx.x * blockDim.x + threadIdx.x;
    if (i >= total) return;
    int e = (int)(i >> 4);
    int j = (int)(i & 15);
    int s = src[e], d = dst[e];
    atomicAdd(&t[(long)d * H + j], hs[(long)s * H + j]);
}

// ---- epilogue: out = relu(dis*(t+hs) + b); out may alias hs ----
__global__ void k_out(const float* __restrict__ t, const float* __restrict__ hs,
                      const float* __restrict__ dis, const float* __restrict__ b,
                      float* __restrict__ out, int n) {
    int i = blockIdx.x * blockDim.x + threadIdx.x;
    if (i >= n * H) return;
    int node = i >> 4, j = i & 15;
    float v = dis[node] * (t[i] + hs[i]) + b[j];
    out[i] = fmaxf(v, 0.0f);
}

// ---- layer-2 linear (in-place): h[n][:] = (h[n][:] @ W2) * dis[n] ----
__global__ void k_lin2(float* __restrict__ h, const float* __restrict__ W2,
                       const float* __restrict__ dis, int n) {
    __shared__ float w[H * H];
    int tid = threadIdx.x;
    if (tid < H * H) w[tid] = W2[tid];
    __syncthreads();
    int node = blockIdx.x * blockDim.x + tid;
    if (node >= n) return;
    float hv[H];
#pragma unroll
    for (int k = 0; k < H; k++) hv[k] = h[(long)node * H + k];
    float d = dis[node];
    float res[H];
#pragma unroll
    for (int j = 0; j < H; j++) {
        float acc = 0.0f;
#pragma unroll
        for (int k = 0; k < H; k++) acc += hv[k] * w[k * H + j];
        res[j] = acc * d;
    }
#pragma unroll
    for (int j = 0; j < H; j++) h[(long)node * H + j] = res[j];
}

// ---- pool: pooled[batch[n]][j] = max(...) via int atomicMax (values >= 0) ----
__global__ void k_pool(const float* __restrict__ h, const int* __restrict__ batch,
                       float* __restrict__ pooled, int n) {
    int i = blockIdx.x * blockDim.x + threadIdx.x;
    if (i >= n * H) return;
    int node = i >> 4, j = i & 15;
    atomicMax((int*)&pooled[(long)batch[node] * H + j], __float_as_int(h[i]));
}

// ---- head: logits = pooled @ Wl + bl, then log_softmax ----
__global__ void k_head(const float* __restrict__ pooled, const float* __restrict__ Wl,
                       const float* __restrict__ bl, float* __restrict__ out) {
    __shared__ float w[H * C];
    __shared__ float b[C];
    int tid = threadIdx.x;
    if (tid < H * C) w[tid] = Wl[tid];
    if (tid < C) b[tid] = bl[tid];
    __syncthreads();
    int g = blockIdx.x * blockDim.x + tid;
    if (g >= G_GRAPHS) return;
    float p[H];
#pragma unroll
    for (int k = 0; k < H; k++) p[k] = fmaxf(pooled[g * H + k], 0.0f);
    float l[C];
    float m = -1e30f;
#pragma unroll
    for (int c = 0; c < C; c++) {
        float acc = b[c];
#pragma unroll
        for (int k = 0; k < H; k++) acc += p[k] * w[k * C + c];
        l[c] = acc;
        m = fmaxf(m, acc);
    }
    float s = 0.0f;
#pragma unroll
    for (int c = 0; c < C; c++) s += expf(l[c] - m);
    float lse = logf(s);
#pragma unroll
    for (int c = 0; c < C; c++) out[g * C + c] = l[c] - m - lse;
}

extern "C" void kernel_launch(void* const* d_in, const int* in_sizes, int n_in,
                              void* d_out, int out_size, void* d_ws, size_t ws_size,
                              hipStream_t stream) {
    const float* x    = (const float*)d_in[0];
    const int*   eidx = (const int*)d_in[1];
    const int*   batch= (const int*)d_in[2];
    const float* W1   = (const float*)d_in[3];
    const float* b1   = (const float*)d_in[4];
    const float* W2   = (const float*)d_in[5];
    const float* b2   = (const float*)d_in[6];
    const float* Wl   = (const float*)d_in[7];
    const float* bl   = (const float*)d_in[8];
    float* out = (float*)d_out;

    int N = in_sizes[0] / F_IN;
    int E = in_sizes[1] / 2;
    const int* src = eidx;
    const int* dst = eidx + E;

    size_t featBytes = (size_t)N * H * sizeof(float);
    char* ws = (char*)d_ws;
    float* A      = (float*)ws;                          // scatter accumulator
    float* B      = (float*)(ws + featBytes);            // hs / h (in-place)
    float* dis    = (float*)(ws + 2 * featBytes);
    int*   deg    = (int*)  (ws + 2 * featBytes + (size_t)N * 4);
    float* pooled = (float*)(ws + 2 * featBytes + 2 * (size_t)N * 4);

    const int BS = 256;
    long totNH = (long)N * H;
    long totEH = (long)E * H;
    int  gN    = (N + BS - 1) / BS;
    int  gE    = (E + BS - 1) / BS;
    int  gNH   = (int)((totNH + BS - 1) / BS);
    int  gEH   = (int)((totEH + BS - 1) / BS);

    // degree + normalization
    hipMemsetAsync(deg, 0, (size_t)N * 4, stream);
    k_deg<<<gE, BS, 0, stream>>>(dst, deg, E);
    k_dis<<<gN, BS, 0, stream>>>(deg, dis, N);

    // layer 1
    hipMemsetAsync(A, 0, featBytes, stream);
    k_lin1<<<gNH, BS, 0, stream>>>(x, W1, dis, B, N);
    k_scatter<<<gEH, BS, 0, stream>>>(src, dst, B, A, totEH);
    k_out<<<gNH, BS, 0, stream>>>(A, B, dis, b1, B, N);

    // layer 2
    k_lin2<<<gN, BS, 0, stream>>>(B, W2, dis, N);
    hipMemsetAsync(A, 0, featBytes, stream);
    k_scatter<<<gEH, BS, 0, stream>>>(src, dst, B, A, totEH);
    k_out<<<gNH, BS, 0, stream>>>(A, B, dis, b2, B, N);

    // pooling + head
    hipMemsetAsync(pooled, 0, (size_t)G_GRAPHS * H * sizeof(float), stream);
    k_pool<<<gNH, BS, 0, stream>>>(B, batch, pooled, N);
    k_head<<<(G_GRAPHS + BS - 1) / BS, BS, 0, stream>>>(pooled, Wl, bl, out);
}